// Round 3
// baseline (367.260 us; speedup 1.0000x reference)
//
#include <hip/hip_runtime.h>
#include <math.h>

#define THREADS 256
#define GAMMA 0.99

// ---------- padded LDS index ----------
template<int LPT>
__device__ __forceinline__ int padi(int i) { return i + (i >> LPT); }

// ---------- block-wide exclusive scan of linear transforms x -> g*x + v ----------
template<int NW>
__device__ __forceinline__ void block_compose_excl(int tid, double g, double v,
                                                   double& eg, double& ev,
                                                   double* lg, double* lv) {
    const int lane = tid & 63, wave = tid >> 6;
    double ig = g, iv = v;
#pragma unroll
    for (int k = 1; k < 64; k <<= 1) {
        double og = __shfl_up(ig, k);
        double ov = __shfl_up(iv, k);
        if (lane >= k) { iv = fma(ig, ov, iv); ig *= og; }
    }
    double weg = __shfl_up(ig, 1);
    double wev = __shfl_up(iv, 1);
    if (lane == 0) { weg = 1.0; wev = 0.0; }
    if (lane == 63) { lg[wave] = ig; lv[wave] = iv; }
    __syncthreads();
    double bg = 1.0, bv = 0.0;
    for (int w = 0; w < wave; ++w) { bv = fma(lg[w], bv, lv[w]); bg *= lg[w]; }
    eg = weg * bg;
    ev = fma(weg, bv, wev);
}

// ---------- block-wide exclusive additive scan of a pair ----------
template<int NW>
__device__ __forceinline__ void block_add_excl2(int tid, double a, double b,
                                                double& ea, double& eb,
                                                double* la, double* lb) {
    const int lane = tid & 63, wave = tid >> 6;
    double ia = a, ib = b;
#pragma unroll
    for (int k = 1; k < 64; k <<= 1) {
        double oa = __shfl_up(ia, k);
        double ob = __shfl_up(ib, k);
        if (lane >= k) { ia += oa; ib += ob; }
    }
    double wea = __shfl_up(ia, 1);
    double web = __shfl_up(ib, 1);
    if (lane == 0) { wea = 0.0; web = 0.0; }
    if (lane == 63) { la[wave] = ia; lb[wave] = ib; }
    __syncthreads();
    double ba = 0.0, bb = 0.0;
    for (int w = 0; w < wave; ++w) { ba += la[w]; bb += lb[w]; }
    ea = wea + ba;
    eb = web + bb;
}

__global__ __launch_bounds__(256) void rs_init_flags(int* __restrict__ flags, int n) {
    const int i = blockIdx.x * blockDim.x + threadIdx.x;
    if (i < n) flags[i] = 0;
}

// ================= single-pass decoupled-lookback kernel =================
// ws layout (n = nchunk doubles each): aA | aPs | aPq | aP2 | iR | iS1 | iS2 | flags(int[n])
// flag: 0 = none, 1 = aggregate ready, 2 = inclusive ready
template<int PT, int LPT, int LOG2CH>
__global__ __launch_bounds__(THREADS) void rs_onepass(const float* __restrict__ in,
                                                      float* __restrict__ out,
                                                      double* __restrict__ ws,
                                                      int* __restrict__ flags, int nchunk) {
    constexpr int CHUNKE = THREADS * PT;
    __shared__ float sbuf[CHUNKE + THREADS];
    __shared__ double lg[4], lv[4], r1[4], r2[4], r3[4], la[4], lb[4], inc[3];
    const int tid = threadIdx.x, lane = tid & 63, wave = tid >> 6;
    const int chunk = blockIdx.x;
    double* aA  = ws;
    double* aPs = ws + nchunk;
    double* aPq = ws + 2 * (size_t)nchunk;
    double* aP2 = ws + 3 * (size_t)nchunk;
    double* iR  = ws + 4 * (size_t)nchunk;
    double* iS1 = ws + 5 * (size_t)nchunk;
    double* iS2 = ws + 6 * (size_t)nchunk;

    const float* src = in + (size_t)chunk * CHUNKE + (size_t)tid * PT;
    float rv[PT];
#pragma unroll
    for (int q = 0; q < PT / 4; ++q) {
        const float4 t = ((const float4*)src)[q];
        rv[4 * q] = t.x; rv[4 * q + 1] = t.y; rv[4 * q + 2] = t.z; rv[4 * q + 3] = t.w;
    }
    const float gf = (float)GAMMA;
    float p = 0.f, psum = 0.f, pq = 0.f, p2 = 0.f, gp = 1.f;
#pragma unroll
    for (int j = 0; j < PT; ++j) {
        p = fmaf(gf, p, rv[j]);
        gp *= gf;
        psum += p;
        pq = fmaf(gp, p, pq);
        p2 = fmaf(p, p, p2);
    }
    const double g = GAMMA;
    double gPT = g;
#pragma unroll
    for (int e = 0; e < LPT; ++e) gPT *= gPT;      // g^PT
    double gC = g;
#pragma unroll
    for (int e = 0; e < LOG2CH; ++e) gC *= gC;     // g^CHUNKE

    // block compose scan (zero-init within chunk)
    double eg, ev;
    block_compose_excl<4>(tid, gPT, (double)p, eg, ev, lg, lv);
    const double rho = ev, gexc = eg;

    const double G1 = g * (1.0 - gPT) / (1.0 - g);
    const double G2 = g * g * (1.0 - gPT * gPT) / (1.0 - g * g);
    const double G1C = g * (1.0 - gC) / (1.0 - g);
    const double G2C = g * g * (1.0 - gC * gC) / (1.0 - g * g);

    // zero-init chunk aggregates
    double c1 = fma(rho, G1, (double)psum);
    double c2 = gexc * fma(rho, G2, (double)pq);
    double c3 = fma(rho * rho, G2, fma(2.0 * rho, (double)pq, (double)p2));
#pragma unroll
    for (int k = 32; k > 0; k >>= 1) {
        c1 += __shfl_down(c1, k);
        c2 += __shfl_down(c2, k);
        c3 += __shfl_down(c3, k);
    }
    if (lane == 0) { r1[wave] = c1; r2[wave] = c2; r3[wave] = c3; }
    __syncthreads();

    if (wave == 0) {
        // thread 0 assembles block aggregates
        double A = 0.0, Ps = 0.0, Pq = 0.0, P2s = 0.0;
        if (lane == 0) {
#pragma unroll
            for (int w = 0; w < 4; ++w) A = fma(lg[w], A, lv[w]);
            Ps  = r1[0] + r1[1] + r1[2] + r1[3];
            Pq  = r2[0] + r2[1] + r2[2] + r2[3];
            P2s = r3[0] + r3[1] + r3[2] + r3[3];
            if (chunk > 0) {
                __hip_atomic_store(&aA[chunk],  A,   __ATOMIC_RELAXED, __HIP_MEMORY_SCOPE_AGENT);
                __hip_atomic_store(&aPs[chunk], Ps,  __ATOMIC_RELAXED, __HIP_MEMORY_SCOPE_AGENT);
                __hip_atomic_store(&aPq[chunk], Pq,  __ATOMIC_RELAXED, __HIP_MEMORY_SCOPE_AGENT);
                __hip_atomic_store(&aP2[chunk], P2s, __ATOMIC_RELAXED, __HIP_MEMORY_SCOPE_AGENT);
                __hip_atomic_store(&flags[chunk], 1, __ATOMIC_RELEASE, __HIP_MEMORY_SCOPE_AGENT);
            }
        }
        double Rin = 0.0, S1C = 0.0, S2C = 0.0;
        if (chunk > 0) {
            // outer accumulated map M (identity)
            double Ma = 1.0, Mb = 0.0, Mc = 0.0, Md = 0.0, Me = 0.0, Mf = 0.0, Mh = 0.0;
            int wend = chunk - 1;
            for (;;) {
                const int j = wend - 63 + lane;
                int f = 2;
                if (j >= 0) f = __hip_atomic_load(&flags[j], __ATOMIC_ACQUIRE, __HIP_MEMORY_SCOPE_AGENT);
                const unsigned long long m2 = __ballot(f == 2);
                const unsigned long long m1 = __ballot(f >= 1);
                if (m2 != 0) {
                    const int l2 = 63 - __builtin_clzll(m2);
                    const unsigned long long need = (l2 == 63) ? 0ull : (~0ull << (l2 + 1));
                    if ((m1 & need) == need) {
                        const int jj = wend - 63 + l2;
                        double sR = 0.0, s1v = 0.0, s2v = 0.0;
                        if (lane == l2 && jj >= 0) {
                            sR  = __hip_atomic_load(&iR[jj],  __ATOMIC_RELAXED, __HIP_MEMORY_SCOPE_AGENT);
                            s1v = __hip_atomic_load(&iS1[jj], __ATOMIC_RELAXED, __HIP_MEMORY_SCOPE_AGENT);
                            s2v = __hip_atomic_load(&iS2[jj], __ATOMIC_RELAXED, __HIP_MEMORY_SCOPE_AGENT);
                        }
                        sR = __shfl(sR, l2); s1v = __shfl(s1v, l2); s2v = __shfl(s2v, l2);
                        double a = 1.0, b = 0.0, cc = 0.0, d = 0.0, e = 0.0, ff = 0.0, h = 0.0;
                        if (lane > l2) {
                            a = gC; cc = G1C; e = G2C;
                            b  = __hip_atomic_load(&aA[j],  __ATOMIC_RELAXED, __HIP_MEMORY_SCOPE_AGENT);
                            d  = __hip_atomic_load(&aPs[j], __ATOMIC_RELAXED, __HIP_MEMORY_SCOPE_AGENT);
                            ff = 2.0 * __hip_atomic_load(&aPq[j], __ATOMIC_RELAXED, __HIP_MEMORY_SCOPE_AGENT);
                            h  = __hip_atomic_load(&aP2[j], __ATOMIC_RELAXED, __HIP_MEMORY_SCOPE_AGENT);
                        }
#pragma unroll
                        for (int k = 1; k < 64; k <<= 1) {
                            const double a2 = __shfl_down(a, k),  b2 = __shfl_down(b, k);
                            const double c2_ = __shfl_down(cc, k), d2 = __shfl_down(d, k);
                            const double e2 = __shfl_down(e, k),  f2 = __shfl_down(ff, k);
                            const double h2 = __shfl_down(h, k);
                            if (lane + k < 64) {
                                const double na = a2 * a;
                                const double nb = fma(a2, b, b2);
                                const double nc = fma(c2_, a, cc);
                                const double nd = fma(c2_, b, d) + d2;
                                const double ne = fma(e2, a * a, e);
                                const double nf = fma(2.0 * e2, a * b, fma(f2, a, ff));
                                const double nh = fma(e2, b * b, fma(f2, b, h)) + h2;
                                a = na; b = nb; cc = nc; d = nd; e = ne; ff = nf; h = nh;
                            }
                        }
                        // lane 0: apply window map to state, then outer map
                        const double R1  = fma(a, sR, b);
                        const double S11 = s1v + fma(cc, sR, d);
                        const double S21 = s2v + fma(e, sR * sR, fma(ff, sR, h));
                        Rin = fma(Ma, R1, Mb);
                        S1C = S11 + fma(Mc, R1, Md);
                        S2C = S21 + fma(Me, R1 * R1, fma(Mf, R1, Mh));
                        break;
                    }
                } else if (m1 == ~0ull) {
                    // fold whole window of aggregates into outer map, move back
                    double a = gC, cc = G1C, e = G2C;
                    double b  = __hip_atomic_load(&aA[j],  __ATOMIC_RELAXED, __HIP_MEMORY_SCOPE_AGENT);
                    double d  = __hip_atomic_load(&aPs[j], __ATOMIC_RELAXED, __HIP_MEMORY_SCOPE_AGENT);
                    double ff = 2.0 * __hip_atomic_load(&aPq[j], __ATOMIC_RELAXED, __HIP_MEMORY_SCOPE_AGENT);
                    double h  = __hip_atomic_load(&aP2[j], __ATOMIC_RELAXED, __HIP_MEMORY_SCOPE_AGENT);
#pragma unroll
                    for (int k = 1; k < 64; k <<= 1) {
                        const double a2 = __shfl_down(a, k),  b2 = __shfl_down(b, k);
                        const double c2_ = __shfl_down(cc, k), d2 = __shfl_down(d, k);
                        const double e2 = __shfl_down(e, k),  f2 = __shfl_down(ff, k);
                        const double h2 = __shfl_down(h, k);
                        if (lane + k < 64) {
                            const double na = a2 * a;
                            const double nb = fma(a2, b, b2);
                            const double nc = fma(c2_, a, cc);
                            const double nd = fma(c2_, b, d) + d2;
                            const double ne = fma(e2, a * a, e);
                            const double nf = fma(2.0 * e2, a * b, fma(f2, a, ff));
                            const double nh = fma(e2, b * b, fma(f2, b, h)) + h2;
                            a = na; b = nb; cc = nc; d = nd; e = ne; ff = nf; h = nh;
                        }
                    }
                    // M_new = M_old ∘ W  (window first, then old outer)
                    const double Wa = a, Wb = b, Wc = cc, Wd = d, We = e, Wf = ff, Wh = h;
                    const double nMa = Ma * Wa;
                    const double nMb = fma(Ma, Wb, Mb);
                    const double nMc = fma(Mc, Wa, Wc);
                    const double nMd = Wd + fma(Mc, Wb, Md);
                    const double nMe = fma(Me, Wa * Wa, We);
                    const double nMf = Wf + fma(2.0 * Me, Wa * Wb, Mf * Wa);
                    const double nMh = Wh + fma(Me, Wb * Wb, fma(Mf, Wb, Mh));
                    Ma = nMa; Mb = nMb; Mc = nMc; Md = nMd; Me = nMe; Mf = nMf; Mh = nMh;
                    wend -= 64;
                    continue;
                } else {
                    __builtin_amdgcn_s_sleep(1);
                    continue;
                }
                __builtin_amdgcn_s_sleep(1);
            }
        }
        if (lane == 0) {
            // publish inclusive ASAP to unblock successors
            const double RI  = fma(gC, Rin, A);
            const double S1I = S1C + fma(Rin, G1C, Ps);
            const double S2I = S2C + fma(Rin * Rin, G2C, fma(2.0 * Rin, Pq, P2s));
            __hip_atomic_store(&iR[chunk],  RI,  __ATOMIC_RELAXED, __HIP_MEMORY_SCOPE_AGENT);
            __hip_atomic_store(&iS1[chunk], S1I, __ATOMIC_RELAXED, __HIP_MEMORY_SCOPE_AGENT);
            __hip_atomic_store(&iS2[chunk], S2I, __ATOMIC_RELAXED, __HIP_MEMORY_SCOPE_AGENT);
            __hip_atomic_store(&flags[chunk], 2, __ATOMIC_RELEASE, __HIP_MEMORY_SCOPE_AGENT);
            inc[0] = Rin; inc[1] = S1C; inc[2] = S2C;
        }
    }
    __syncthreads();
    const double RinC = inc[0], S1Cb = inc[1], S2Cb = inc[2];

    const double rin = fma(gexc, RinC, rho);    // true incoming R for this thread's segment
    const double s1 = fma(rin, G1, (double)psum);
    const double s2 = fma(rin * rin, G2, fma(2.0 * rin, (double)pq, (double)p2));
    double ea, eb;
    block_add_excl2<4>(tid, s1, s2, ea, eb, la, lb);
    const double S1b = S1Cb + ea;
    const double S2b = S2Cb + eb;

    const int a0 = padi<LPT>(tid * PT);

    if (chunk == 0) {
        double R = rin, S1 = S1b, S2 = S2b;
        const size_t gbase = (size_t)tid * PT;
        for (int j = 0; j < PT; ++j) {
            const float rf = rv[j];
            R = fma(g, R, (double)rf);
            S1 += R;
            S2 = fma(R, R, S2);
            float ov;
            if (gbase + j == 0) {
                ov = rf;
            } else {
                const double cnt = (double)(gbase + j + 1);
                const double inv = 1.0 / cnt;
                const double mean = S1 * inv;
                double var = fma(S2, inv, -(mean * mean));
                var = var > 0.0 ? var : 0.0;
                double sd = sqrt(var);
                sd = sd > 1e-8 ? sd : 1e-8;
                ov = (float)((double)rf / sd);
            }
            sbuf[a0 + j] = ov;
        }
    } else {
        float R = (float)rin;
        float ls1 = 0.f, ls2 = 0.f;
        const float S1bf = (float)S1b, S2bf = (float)S2b;
        const float base_cnt = (float)((size_t)chunk * CHUNKE + (size_t)tid * PT);
#pragma unroll
        for (int j = 0; j < PT; ++j) {
            const float rf = rv[j];
            R = fmaf(gf, R, rf);
            ls1 += R;
            ls2 = fmaf(R, R, ls2);
            const float cnt = base_cnt + (float)(j + 1);
            const float inv = 1.0f / cnt;
            const float S1f = S1bf + ls1;
            const float S2f = S2bf + ls2;
            const float mean = S1f * inv;
            float var = fmaf(S2f, inv, -(mean * mean));
            var = var > 0.f ? var : 0.f;
            float sd = sqrtf(var);
            sd = sd > 1e-8f ? sd : 1e-8f;
            sbuf[a0 + j] = rf / sd;
        }
    }
    __syncthreads();

    float* dst = out + (size_t)chunk * CHUNKE;
    for (int i = tid * 4; i < CHUNKE; i += THREADS * 4) {
        const int pp = padi<LPT>(i);
        *(float4*)(dst + i) = make_float4(sbuf[pp], sbuf[pp + 1], sbuf[pp + 2], sbuf[pp + 3]);
    }
}

// ================= fallback 3-phase path (unchanged from round 2) =================
template<int PT, int LPT>
__global__ __launch_bounds__(THREADS) void rs_phase1(const float* __restrict__ in,
                                                     double* __restrict__ ws, int nchunk) {
    constexpr int CHUNKE = THREADS * PT;
    __shared__ double lg[4], lv[4], r1[4], r2[4], r3[4];
    const int tid = threadIdx.x, lane = tid & 63, wave = tid >> 6;
    const int chunk = blockIdx.x;
    const float* src = in + (size_t)chunk * CHUNKE + (size_t)tid * PT;

    float rv[PT];
#pragma unroll
    for (int q = 0; q < PT / 4; ++q) {
        const float4 t = ((const float4*)src)[q];
        rv[4 * q] = t.x; rv[4 * q + 1] = t.y; rv[4 * q + 2] = t.z; rv[4 * q + 3] = t.w;
    }
    const float gf = (float)GAMMA;
    float p = 0.f, psum = 0.f, pq = 0.f, p2 = 0.f, gp = 1.f;
#pragma unroll
    for (int j = 0; j < PT; ++j) {
        p = fmaf(gf, p, rv[j]);
        gp *= gf;
        psum += p;
        pq = fmaf(gp, p, pq);
        p2 = fmaf(p, p, p2);
    }
    const double g = GAMMA;
    double gPT = g;
#pragma unroll
    for (int e = 0; e < LPT; ++e) gPT *= gPT;

    double eg, ev;
    block_compose_excl<4>(tid, gPT, (double)p, eg, ev, lg, lv);
    const double rho = ev, gexc = eg;

    const double G1 = g * (1.0 - gPT) / (1.0 - g);
    const double G2 = g * g * (1.0 - gPT * gPT) / (1.0 - g * g);
    double c1 = fma(rho, G1, (double)psum);
    double c2 = gexc * fma(rho, G2, (double)pq);
    double c3 = fma(rho * rho, G2, fma(2.0 * rho, (double)pq, (double)p2));
#pragma unroll
    for (int k = 32; k > 0; k >>= 1) {
        c1 += __shfl_down(c1, k);
        c2 += __shfl_down(c2, k);
        c3 += __shfl_down(c3, k);
    }
    if (lane == 0) { r1[wave] = c1; r2[wave] = c2; r3[wave] = c3; }
    __syncthreads();
    if (tid == 0) {
        double A = 0.0;
#pragma unroll
        for (int w = 0; w < 4; ++w) A = fma(lg[w], A, lv[w]);
        ws[chunk]              = A;
        ws[nchunk + chunk]     = r1[0] + r1[1] + r1[2] + r1[3];
        ws[2 * nchunk + chunk] = r2[0] + r2[1] + r2[2] + r2[3];
        ws[3 * nchunk + chunk] = r3[0] + r3[1] + r3[2] + r3[3];
    }
}

template<int CPT, int LOG2CHUNK>
__global__ __launch_bounds__(1024) void rs_phase2(double* __restrict__ ws, int nchunk) {
    __shared__ double lg[16], lv[16], la[16], lb[16];
    const int t = threadIdx.x;
    const double g = GAMMA;
    double gC = g;
#pragma unroll
    for (int e = 0; e < LOG2CHUNK; ++e) gC *= gC;

    double A[CPT], Ps[CPT], Pq[CPT], P2[CPT];
    const int c0 = t * CPT;
#pragma unroll
    for (int i = 0; i < CPT; ++i) {
        const int c = c0 + i;
        const bool ok = c < nchunk;
        A[i]  = ok ? ws[c] : 0.0;
        Ps[i] = ok ? ws[nchunk + c] : 0.0;
        Pq[i] = ok ? ws[2 * nchunk + c] : 0.0;
        P2[i] = ok ? ws[3 * nchunk + c] : 0.0;
    }
    double mg = 1.0, mv = 0.0;
#pragma unroll
    for (int i = 0; i < CPT; ++i) { mv = fma(gC, mv, A[i]); mg *= gC; }

    double eg, ev;
    block_compose_excl<16>(t, mg, mv, eg, ev, lg, lv);

    const double G1C = g * (1.0 - gC) / (1.0 - g);
    const double G2C = g * g * (1.0 - gC * gC) / (1.0 - g * g);
    double Rin[CPT + 1];
    Rin[0] = ev;
    double s1[CPT], s2[CPT];
#pragma unroll
    for (int i = 0; i < CPT; ++i) {
        s1[i] = fma(Rin[i], G1C, Ps[i]);
        s2[i] = fma(Rin[i] * Rin[i], G2C, fma(2.0 * Rin[i], Pq[i], P2[i]));
        Rin[i + 1] = fma(gC, Rin[i], A[i]);
    }
    double ts1 = 0.0, ts2 = 0.0;
#pragma unroll
    for (int i = 0; i < CPT; ++i) { ts1 += s1[i]; ts2 += s2[i]; }
    double ea, eb;
    block_add_excl2<16>(t, ts1, ts2, ea, eb, la, lb);
#pragma unroll
    for (int i = 0; i < CPT; ++i) {
        const int c = c0 + i;
        if (c < nchunk) {
            ws[4 * nchunk + c] = Rin[i];
            ws[5 * nchunk + c] = ea;
            ws[6 * nchunk + c] = eb;
        }
        ea += s1[i];
        eb += s2[i];
    }
}

template<int PT, int LPT>
__global__ __launch_bounds__(THREADS) void rs_phase3(const float* __restrict__ in,
                                                     float* __restrict__ out,
                                                     const double* __restrict__ ws, int nchunk) {
    constexpr int CHUNKE = THREADS * PT;
    __shared__ float sbuf[CHUNKE + THREADS];
    __shared__ double lg[4], lv[4], la[4], lb[4];
    const int tid = threadIdx.x;
    const int chunk = blockIdx.x;
    const float* src = in + (size_t)chunk * CHUNKE + (size_t)tid * PT;

    float rv[PT];
#pragma unroll
    for (int q = 0; q < PT / 4; ++q) {
        const float4 t = ((const float4*)src)[q];
        rv[4 * q] = t.x; rv[4 * q + 1] = t.y; rv[4 * q + 2] = t.z; rv[4 * q + 3] = t.w;
    }
    const float gf = (float)GAMMA;
    float p = 0.f, psum = 0.f, pq = 0.f, p2 = 0.f, gp = 1.f;
#pragma unroll
    for (int j = 0; j < PT; ++j) {
        p = fmaf(gf, p, rv[j]);
        gp *= gf;
        psum += p;
        pq = fmaf(gp, p, pq);
        p2 = fmaf(p, p, p2);
    }
    const double g = GAMMA;
    double gPT = g;
#pragma unroll
    for (int e = 0; e < LPT; ++e) gPT *= gPT;

    double eg, ev;
    block_compose_excl<4>(tid, gPT, (double)p, eg, ev, lg, lv);

    const double RinC = ws[4 * nchunk + chunk];
    const double S1C  = ws[5 * nchunk + chunk];
    const double S2C  = ws[6 * nchunk + chunk];
    const double rin  = fma(eg, RinC, ev);

    const double G1 = g * (1.0 - gPT) / (1.0 - g);
    const double G2 = g * g * (1.0 - gPT * gPT) / (1.0 - g * g);
    const double s1 = fma(rin, G1, (double)psum);
    const double s2 = fma(rin * rin, G2, fma(2.0 * rin, (double)pq, (double)p2));
    double ea, eb;
    block_add_excl2<4>(tid, s1, s2, ea, eb, la, lb);
    const double S1b = S1C + ea;
    const double S2b = S2C + eb;

    const int a0 = padi<LPT>(tid * PT);

    if (chunk == 0) {
        double R = rin, S1 = S1b, S2 = S2b;
        const size_t gbase = (size_t)tid * PT;
        for (int j = 0; j < PT; ++j) {
            const float rf = rv[j];
            R = fma(g, R, (double)rf);
            S1 += R;
            S2 = fma(R, R, S2);
            float ov;
            if (gbase + j == 0) {
                ov = rf;
            } else {
                const double cnt = (double)(gbase + j + 1);
                const double inv = 1.0 / cnt;
                const double mean = S1 * inv;
                double var = fma(S2, inv, -(mean * mean));
                var = var > 0.0 ? var : 0.0;
                double sd = sqrt(var);
                sd = sd > 1e-8 ? sd : 1e-8;
                ov = (float)((double)rf / sd);
            }
            sbuf[a0 + j] = ov;
        }
    } else {
        float R = (float)rin;
        float ls1 = 0.f, ls2 = 0.f;
        const float S1bf = (float)S1b, S2bf = (float)S2b;
        const float base_cnt = (float)((size_t)chunk * CHUNKE + (size_t)tid * PT);
#pragma unroll
        for (int j = 0; j < PT; ++j) {
            const float rf = rv[j];
            R = fmaf(gf, R, rf);
            ls1 += R;
            ls2 = fmaf(R, R, ls2);
            const float cnt = base_cnt + (float)(j + 1);
            const float inv = 1.0f / cnt;
            const float S1f = S1bf + ls1;
            const float S2f = S2bf + ls2;
            const float mean = S1f * inv;
            float var = fmaf(S2f, inv, -(mean * mean));
            var = var > 0.f ? var : 0.f;
            float sd = sqrtf(var);
            sd = sd > 1e-8f ? sd : 1e-8f;
            sbuf[a0 + j] = rf / sd;
        }
    }
    __syncthreads();

    float* dst = out + (size_t)chunk * CHUNKE;
    for (int i = tid * 4; i < CHUNKE; i += THREADS * 4) {
        const int pp = padi<LPT>(i);
        *(float4*)(dst + i) = make_float4(sbuf[pp], sbuf[pp + 1], sbuf[pp + 2], sbuf[pp + 3]);
    }
}

extern "C" void kernel_launch(void* const* d_in, const int* in_sizes, int n_in,
                              void* d_out, int out_size, void* d_ws, size_t ws_size,
                              hipStream_t stream) {
    (void)n_in; (void)out_size;
    const float* in = (const float*)d_in[0];
    float* out = (float*)d_out;
    double* ws = (double*)d_ws;
    const int n = in_sizes[0];

    const int nc = n / 4096;
    const size_t need_lb = (size_t)7 * nc * sizeof(double) + (size_t)nc * sizeof(int);
    if ((n % 4096) == 0 && nc >= 1 && ws_size >= need_lb) {
        int* flags = (int*)(ws + 7 * (size_t)nc);
        rs_init_flags<<<(nc + 255) / 256, 256, 0, stream>>>(flags, nc);
        rs_onepass<16, 4, 12><<<nc, THREADS, 0, stream>>>(in, out, ws, flags, nc);
    } else if ((n % 4096) == 0 && nc >= 1 && nc <= 4096 &&
               ws_size >= (size_t)7 * nc * sizeof(double)) {
        rs_phase1<16, 4><<<nc, THREADS, 0, stream>>>(in, ws, nc);
        rs_phase2<4, 12><<<1, 1024, 0, stream>>>(ws, nc);
        rs_phase3<16, 4><<<nc, THREADS, 0, stream>>>(in, out, ws, nc);
    } else {
        const int nc64 = n / 16384;
        rs_phase1<64, 6><<<nc64, THREADS, 0, stream>>>(in, ws, nc64);
        rs_phase2<1, 14><<<1, 1024, 0, stream>>>(ws, nc64);
        rs_phase3<64, 6><<<nc64, THREADS, 0, stream>>>(in, out, ws, nc64);
    }
}

// Round 4
// 202.650 us; speedup vs baseline: 1.8123x; 1.8123x over previous
//
#include <hip/hip_runtime.h>
#include <hip/hip_cooperative_groups.h>
#include <math.h>

namespace cg = cooperative_groups;

#define THREADS 256
#define GAMMA 0.99

// ---------- padded LDS index ----------
template<int LPT>
__device__ __forceinline__ int padi(int i) { return i + (i >> LPT); }

// ---------- block-wide exclusive scan of linear transforms x -> g*x + v ----------
template<int NW>
__device__ __forceinline__ void block_compose_excl(int tid, double g, double v,
                                                   double& eg, double& ev,
                                                   double* lg, double* lv) {
    const int lane = tid & 63, wave = tid >> 6;
    double ig = g, iv = v;
#pragma unroll
    for (int k = 1; k < 64; k <<= 1) {
        double og = __shfl_up(ig, k);
        double ov = __shfl_up(iv, k);
        if (lane >= k) { iv = fma(ig, ov, iv); ig *= og; }
    }
    double weg = __shfl_up(ig, 1);
    double wev = __shfl_up(iv, 1);
    if (lane == 0) { weg = 1.0; wev = 0.0; }
    if (lane == 63) { lg[wave] = ig; lv[wave] = iv; }
    __syncthreads();
    double bg = 1.0, bv = 0.0;
    for (int w = 0; w < wave; ++w) { bv = fma(lg[w], bv, lv[w]); bg *= lg[w]; }
    eg = weg * bg;
    ev = fma(weg, bv, wev);
}

// ---------- block-wide exclusive additive scan of a pair ----------
template<int NW>
__device__ __forceinline__ void block_add_excl2(int tid, double a, double b,
                                                double& ea, double& eb,
                                                double* la, double* lb) {
    const int lane = tid & 63, wave = tid >> 6;
    double ia = a, ib = b;
#pragma unroll
    for (int k = 1; k < 64; k <<= 1) {
        double oa = __shfl_up(ia, k);
        double ob = __shfl_up(ib, k);
        if (lane >= k) { ia += oa; ib += ob; }
    }
    double wea = __shfl_up(ia, 1);
    double web = __shfl_up(ib, 1);
    if (lane == 0) { wea = 0.0; web = 0.0; }
    if (lane == 63) { la[wave] = ia; lb[wave] = ib; }
    __syncthreads();
    double ba = 0.0, bb = 0.0;
    for (int w = 0; w < wave; ++w) { ba += la[w]; bb += lb[w]; }
    ea = wea + ba;
    eb = web + bb;
}

// ================= single cooperative persistent kernel =================
// ws layout (nchunk doubles each): aA | aPs | aPq | aP2 | iR | iS1 | iS2
template<int PT, int LPT, int LOG2CH>
__global__ __launch_bounds__(THREADS, 4) void rs_coop(const float* __restrict__ in,
                                                      float* __restrict__ out,
                                                      double* __restrict__ ws, int nchunk) {
    constexpr int CHUNKE = THREADS * PT;
    __shared__ float sbuf[CHUNKE + THREADS];
    __shared__ double lg[4], lv[4], r1[4], r2[4], r3[4], la[4], lb[4];
    const int tid = threadIdx.x, lane = tid & 63, wave = tid >> 6;
    cg::grid_group grid = cg::this_grid();

    const double g = GAMMA;
    const float gf = (float)GAMMA;
    double gPT = g;
#pragma unroll
    for (int e = 0; e < LPT; ++e) gPT *= gPT;      // g^PT
    double gC = g;
#pragma unroll
    for (int e = 0; e < LOG2CH; ++e) gC *= gC;     // g^CHUNKE
    const double G1  = g * (1.0 - gPT) / (1.0 - g);
    const double G2  = g * g * (1.0 - gPT * gPT) / (1.0 - g * g);
    const double G1C = g * (1.0 - gC) / (1.0 - g);
    const double G2C = g * g * (1.0 - gC * gC) / (1.0 - g * g);

    double* aA  = ws;
    double* aPs = ws + (size_t)nchunk;
    double* aPq = ws + 2 * (size_t)nchunk;
    double* aP2 = ws + 3 * (size_t)nchunk;
    double* iR  = ws + 4 * (size_t)nchunk;
    double* iS1 = ws + 5 * (size_t)nchunk;
    double* iS2 = ws + 6 * (size_t)nchunk;

    const int cpb = (nchunk + gridDim.x - 1) / gridDim.x;   // chunks per block
    const int c_lo = blockIdx.x * cpb;
    const int c_hi = min(nchunk, c_lo + cpb);

    // ---------------- phase A: per-chunk zero-init aggregates ----------------
    for (int chunk = c_lo; chunk < c_hi; ++chunk) {
        const float* src = in + (size_t)chunk * CHUNKE + (size_t)tid * PT;
        float rv[PT];
#pragma unroll
        for (int q = 0; q < PT / 4; ++q) {
            const float4 t = ((const float4*)src)[q];
            rv[4 * q] = t.x; rv[4 * q + 1] = t.y; rv[4 * q + 2] = t.z; rv[4 * q + 3] = t.w;
        }
        float p = 0.f, psum = 0.f, pq = 0.f, p2 = 0.f, gp = 1.f;
#pragma unroll
        for (int j = 0; j < PT; ++j) {
            p = fmaf(gf, p, rv[j]);
            gp *= gf;
            psum += p;
            pq = fmaf(gp, p, pq);
            p2 = fmaf(p, p, p2);
        }
        double eg, ev;
        block_compose_excl<4>(tid, gPT, (double)p, eg, ev, lg, lv);
        const double rho = ev, gexc = eg;

        double c1 = fma(rho, G1, (double)psum);
        double c2 = gexc * fma(rho, G2, (double)pq);
        double c3 = fma(rho * rho, G2, fma(2.0 * rho, (double)pq, (double)p2));
#pragma unroll
        for (int k = 32; k > 0; k >>= 1) {
            c1 += __shfl_down(c1, k);
            c2 += __shfl_down(c2, k);
            c3 += __shfl_down(c3, k);
        }
        if (lane == 0) { r1[wave] = c1; r2[wave] = c2; r3[wave] = c3; }
        __syncthreads();
        if (tid == 0) {
            double A = 0.0;
#pragma unroll
            for (int w = 0; w < 4; ++w) A = fma(lg[w], A, lv[w]);
            aA[chunk]  = A;
            aPs[chunk] = r1[0] + r1[1] + r1[2] + r1[3];
            aPq[chunk] = r2[0] + r2[1] + r2[2] + r2[3];
            aP2[chunk] = r3[0] + r3[1] + r3[2] + r3[3];
        }
        __syncthreads();   // protect lg/lv/r* for next iteration
    }
    grid.sync();

    // ---------------- phase B: block 0 scans the chunk carries (streaming) ----------------
    if (blockIdx.x == 0) {
        const int CPT = (nchunk + THREADS - 1) / THREADS;
        const int b_lo = tid * CPT;
        const int b_hi = min(nchunk, b_lo + CPT);
        // pass 1: serial compose of own chunks (running pair only)
        double mg = 1.0, mv = 0.0;
        for (int c = b_lo; c < b_hi; ++c) { mv = fma(gC, mv, aA[c]); mg *= gC; }
        double eg2, ev2;
        block_compose_excl<4>(tid, mg, mv, eg2, ev2, lg, lv);
        // pass 2: running totals of s1/s2
        double Rin = ev2, ts1 = 0.0, ts2 = 0.0;
        for (int c = b_lo; c < b_hi; ++c) {
            const double Ac = aA[c], Psc = aPs[c], Pqc = aPq[c], P2c = aP2[c];
            ts1 += fma(Rin, G1C, Psc);
            ts2 += fma(Rin * Rin, G2C, fma(2.0 * Rin, Pqc, P2c));
            Rin = fma(gC, Rin, Ac);
        }
        double ea, eb;
        block_add_excl2<4>(tid, ts1, ts2, ea, eb, la, lb);
        // pass 3: re-walk and write per-chunk carries
        Rin = ev2;
        for (int c = b_lo; c < b_hi; ++c) {
            const double Ac = aA[c], Psc = aPs[c], Pqc = aPq[c], P2c = aP2[c];
            iR[c]  = Rin;
            iS1[c] = ea;
            iS2[c] = eb;
            ea += fma(Rin, G1C, Psc);
            eb += fma(Rin * Rin, G2C, fma(2.0 * Rin, Pqc, P2c));
            Rin = fma(gC, Rin, Ac);
        }
    }
    grid.sync();

    // ---------------- phase C: rebase with true carries, emit scaled rewards ----------------
    for (int chunk = c_lo; chunk < c_hi; ++chunk) {
        __syncthreads();   // protect sbuf/lds arrays from previous iteration
        const float* src = in + (size_t)chunk * CHUNKE + (size_t)tid * PT;
        float rv[PT];
#pragma unroll
        for (int q = 0; q < PT / 4; ++q) {
            const float4 t = ((const float4*)src)[q];
            rv[4 * q] = t.x; rv[4 * q + 1] = t.y; rv[4 * q + 2] = t.z; rv[4 * q + 3] = t.w;
        }
        float p = 0.f, psum = 0.f, pq = 0.f, p2 = 0.f, gp = 1.f;
#pragma unroll
        for (int j = 0; j < PT; ++j) {
            p = fmaf(gf, p, rv[j]);
            gp *= gf;
            psum += p;
            pq = fmaf(gp, p, pq);
            p2 = fmaf(p, p, p2);
        }
        double eg, ev;
        block_compose_excl<4>(tid, gPT, (double)p, eg, ev, lg, lv);

        const double RinC = iR[chunk];
        const double S1C  = iS1[chunk];
        const double S2C  = iS2[chunk];
        const double rin  = fma(eg, RinC, ev);

        const double s1 = fma(rin, G1, (double)psum);
        const double s2 = fma(rin * rin, G2, fma(2.0 * rin, (double)pq, (double)p2));
        double ea, eb;
        block_add_excl2<4>(tid, s1, s2, ea, eb, la, lb);
        const double S1b = S1C + ea;
        const double S2b = S2C + eb;

        const int a0 = padi<LPT>(tid * PT);

        if (chunk == 0) {
            double R = rin, S1 = S1b, S2 = S2b;
            const size_t gbase = (size_t)tid * PT;
            for (int j = 0; j < PT; ++j) {
                const float rf = rv[j];
                R = fma(g, R, (double)rf);
                S1 += R;
                S2 = fma(R, R, S2);
                float ov;
                if (gbase + j == 0) {
                    ov = rf;
                } else {
                    const double cnt = (double)(gbase + j + 1);
                    const double inv = 1.0 / cnt;
                    const double mean = S1 * inv;
                    double var = fma(S2, inv, -(mean * mean));
                    var = var > 0.0 ? var : 0.0;
                    double sd = sqrt(var);
                    sd = sd > 1e-8 ? sd : 1e-8;
                    ov = (float)((double)rf / sd);
                }
                sbuf[a0 + j] = ov;
            }
        } else {
            float R = (float)rin;
            float ls1 = 0.f, ls2 = 0.f;
            const float S1bf = (float)S1b, S2bf = (float)S2b;
            const float base_cnt = (float)((size_t)chunk * CHUNKE + (size_t)tid * PT);
#pragma unroll
            for (int j = 0; j < PT; ++j) {
                const float rf = rv[j];
                R = fmaf(gf, R, rf);
                ls1 += R;
                ls2 = fmaf(R, R, ls2);
                const float cnt = base_cnt + (float)(j + 1);
                const float inv = 1.0f / cnt;
                const float S1f = S1bf + ls1;
                const float S2f = S2bf + ls2;
                const float mean = S1f * inv;
                float var = fmaf(S2f, inv, -(mean * mean));
                var = var > 0.f ? var : 0.f;
                float sd = sqrtf(var);
                sd = sd > 1e-8f ? sd : 1e-8f;
                sbuf[a0 + j] = rf / sd;
            }
        }
        __syncthreads();

        float* dst = out + (size_t)chunk * CHUNKE;
        for (int i = tid * 4; i < CHUNKE; i += THREADS * 4) {
            const int pp = padi<LPT>(i);
            *(float4*)(dst + i) = make_float4(sbuf[pp], sbuf[pp + 1], sbuf[pp + 2], sbuf[pp + 3]);
        }
    }
}

// ================= fallback 3-phase path (round-2, verified) =================
template<int PT, int LPT>
__global__ __launch_bounds__(THREADS) void rs_phase1(const float* __restrict__ in,
                                                     double* __restrict__ ws, int nchunk) {
    constexpr int CHUNKE = THREADS * PT;
    __shared__ double lg[4], lv[4], r1[4], r2[4], r3[4];
    const int tid = threadIdx.x, lane = tid & 63, wave = tid >> 6;
    const int chunk = blockIdx.x;
    const float* src = in + (size_t)chunk * CHUNKE + (size_t)tid * PT;

    float rv[PT];
#pragma unroll
    for (int q = 0; q < PT / 4; ++q) {
        const float4 t = ((const float4*)src)[q];
        rv[4 * q] = t.x; rv[4 * q + 1] = t.y; rv[4 * q + 2] = t.z; rv[4 * q + 3] = t.w;
    }
    const float gf = (float)GAMMA;
    float p = 0.f, psum = 0.f, pq = 0.f, p2 = 0.f, gp = 1.f;
#pragma unroll
    for (int j = 0; j < PT; ++j) {
        p = fmaf(gf, p, rv[j]);
        gp *= gf;
        psum += p;
        pq = fmaf(gp, p, pq);
        p2 = fmaf(p, p, p2);
    }
    const double g = GAMMA;
    double gPT = g;
#pragma unroll
    for (int e = 0; e < LPT; ++e) gPT *= gPT;

    double eg, ev;
    block_compose_excl<4>(tid, gPT, (double)p, eg, ev, lg, lv);
    const double rho = ev, gexc = eg;

    const double G1 = g * (1.0 - gPT) / (1.0 - g);
    const double G2 = g * g * (1.0 - gPT * gPT) / (1.0 - g * g);
    double c1 = fma(rho, G1, (double)psum);
    double c2 = gexc * fma(rho, G2, (double)pq);
    double c3 = fma(rho * rho, G2, fma(2.0 * rho, (double)pq, (double)p2));
#pragma unroll
    for (int k = 32; k > 0; k >>= 1) {
        c1 += __shfl_down(c1, k);
        c2 += __shfl_down(c2, k);
        c3 += __shfl_down(c3, k);
    }
    if (lane == 0) { r1[wave] = c1; r2[wave] = c2; r3[wave] = c3; }
    __syncthreads();
    if (tid == 0) {
        double A = 0.0;
#pragma unroll
        for (int w = 0; w < 4; ++w) A = fma(lg[w], A, lv[w]);
        ws[chunk]              = A;
        ws[nchunk + chunk]     = r1[0] + r1[1] + r1[2] + r1[3];
        ws[2 * nchunk + chunk] = r2[0] + r2[1] + r2[2] + r2[3];
        ws[3 * nchunk + chunk] = r3[0] + r3[1] + r3[2] + r3[3];
    }
}

template<int CPT, int LOG2CHUNK>
__global__ __launch_bounds__(1024) void rs_phase2(double* __restrict__ ws, int nchunk) {
    __shared__ double lg[16], lv[16], la[16], lb[16];
    const int t = threadIdx.x;
    const double g = GAMMA;
    double gC = g;
#pragma unroll
    for (int e = 0; e < LOG2CHUNK; ++e) gC *= gC;

    double A[CPT], Ps[CPT], Pq[CPT], P2[CPT];
    const int c0 = t * CPT;
#pragma unroll
    for (int i = 0; i < CPT; ++i) {
        const int c = c0 + i;
        const bool ok = c < nchunk;
        A[i]  = ok ? ws[c] : 0.0;
        Ps[i] = ok ? ws[nchunk + c] : 0.0;
        Pq[i] = ok ? ws[2 * nchunk + c] : 0.0;
        P2[i] = ok ? ws[3 * nchunk + c] : 0.0;
    }
    double mg = 1.0, mv = 0.0;
#pragma unroll
    for (int i = 0; i < CPT; ++i) { mv = fma(gC, mv, A[i]); mg *= gC; }

    double eg, ev;
    block_compose_excl<16>(t, mg, mv, eg, ev, lg, lv);

    const double G1C = g * (1.0 - gC) / (1.0 - g);
    const double G2C = g * g * (1.0 - gC * gC) / (1.0 - g * g);
    double Rin[CPT + 1];
    Rin[0] = ev;
    double s1[CPT], s2[CPT];
#pragma unroll
    for (int i = 0; i < CPT; ++i) {
        s1[i] = fma(Rin[i], G1C, Ps[i]);
        s2[i] = fma(Rin[i] * Rin[i], G2C, fma(2.0 * Rin[i], Pq[i], P2[i]));
        Rin[i + 1] = fma(gC, Rin[i], A[i]);
    }
    double ts1 = 0.0, ts2 = 0.0;
#pragma unroll
    for (int i = 0; i < CPT; ++i) { ts1 += s1[i]; ts2 += s2[i]; }
    double ea, eb;
    block_add_excl2<16>(t, ts1, ts2, ea, eb, la, lb);
#pragma unroll
    for (int i = 0; i < CPT; ++i) {
        const int c = c0 + i;
        if (c < nchunk) {
            ws[4 * nchunk + c] = Rin[i];
            ws[5 * nchunk + c] = ea;
            ws[6 * nchunk + c] = eb;
        }
        ea += s1[i];
        eb += s2[i];
    }
}

template<int PT, int LPT>
__global__ __launch_bounds__(THREADS) void rs_phase3(const float* __restrict__ in,
                                                     float* __restrict__ out,
                                                     const double* __restrict__ ws, int nchunk) {
    constexpr int CHUNKE = THREADS * PT;
    __shared__ float sbuf[CHUNKE + THREADS];
    __shared__ double lg[4], lv[4], la[4], lb[4];
    const int tid = threadIdx.x;
    const int chunk = blockIdx.x;
    const float* src = in + (size_t)chunk * CHUNKE + (size_t)tid * PT;

    float rv[PT];
#pragma unroll
    for (int q = 0; q < PT / 4; ++q) {
        const float4 t = ((const float4*)src)[q];
        rv[4 * q] = t.x; rv[4 * q + 1] = t.y; rv[4 * q + 2] = t.z; rv[4 * q + 3] = t.w;
    }
    const float gf = (float)GAMMA;
    float p = 0.f, psum = 0.f, pq = 0.f, p2 = 0.f, gp = 1.f;
#pragma unroll
    for (int j = 0; j < PT; ++j) {
        p = fmaf(gf, p, rv[j]);
        gp *= gf;
        psum += p;
        pq = fmaf(gp, p, pq);
        p2 = fmaf(p, p, p2);
    }
    const double g = GAMMA;
    double gPT = g;
#pragma unroll
    for (int e = 0; e < LPT; ++e) gPT *= gPT;

    double eg, ev;
    block_compose_excl<4>(tid, gPT, (double)p, eg, ev, lg, lv);

    const double RinC = ws[4 * nchunk + chunk];
    const double S1C  = ws[5 * nchunk + chunk];
    const double S2C  = ws[6 * nchunk + chunk];
    const double rin  = fma(eg, RinC, ev);

    const double G1 = g * (1.0 - gPT) / (1.0 - g);
    const double G2 = g * g * (1.0 - gPT * gPT) / (1.0 - g * g);
    const double s1 = fma(rin, G1, (double)psum);
    const double s2 = fma(rin * rin, G2, fma(2.0 * rin, (double)pq, (double)p2));
    double ea, eb;
    block_add_excl2<4>(tid, s1, s2, ea, eb, la, lb);
    const double S1b = S1C + ea;
    const double S2b = S2C + eb;

    const int a0 = padi<LPT>(tid * PT);

    if (chunk == 0) {
        double R = rin, S1 = S1b, S2 = S2b;
        const size_t gbase = (size_t)tid * PT;
        for (int j = 0; j < PT; ++j) {
            const float rf = rv[j];
            R = fma(g, R, (double)rf);
            S1 += R;
            S2 = fma(R, R, S2);
            float ov;
            if (gbase + j == 0) {
                ov = rf;
            } else {
                const double cnt = (double)(gbase + j + 1);
                const double inv = 1.0 / cnt;
                const double mean = S1 * inv;
                double var = fma(S2, inv, -(mean * mean));
                var = var > 0.0 ? var : 0.0;
                double sd = sqrt(var);
                sd = sd > 1e-8 ? sd : 1e-8;
                ov = (float)((double)rf / sd);
            }
            sbuf[a0 + j] = ov;
        }
    } else {
        float R = (float)rin;
        float ls1 = 0.f, ls2 = 0.f;
        const float S1bf = (float)S1b, S2bf = (float)S2b;
        const float base_cnt = (float)((size_t)chunk * CHUNKE + (size_t)tid * PT);
#pragma unroll
        for (int j = 0; j < PT; ++j) {
            const float rf = rv[j];
            R = fmaf(gf, R, rf);
            ls1 += R;
            ls2 = fmaf(R, R, ls2);
            const float cnt = base_cnt + (float)(j + 1);
            const float inv = 1.0f / cnt;
            const float S1f = S1bf + ls1;
            const float S2f = S2bf + ls2;
            const float mean = S1f * inv;
            float var = fmaf(S2f, inv, -(mean * mean));
            var = var > 0.f ? var : 0.f;
            float sd = sqrtf(var);
            sd = sd > 1e-8f ? sd : 1e-8f;
            sbuf[a0 + j] = rf / sd;
        }
    }
    __syncthreads();

    float* dst = out + (size_t)chunk * CHUNKE;
    for (int i = tid * 4; i < CHUNKE; i += THREADS * 4) {
        const int pp = padi<LPT>(i);
        *(float4*)(dst + i) = make_float4(sbuf[pp], sbuf[pp + 1], sbuf[pp + 2], sbuf[pp + 3]);
    }
}

extern "C" void kernel_launch(void* const* d_in, const int* in_sizes, int n_in,
                              void* d_out, int out_size, void* d_ws, size_t ws_size,
                              hipStream_t stream) {
    (void)n_in; (void)out_size;
    const float* in = (const float*)d_in[0];
    float* out = (float*)d_out;
    double* ws = (double*)d_ws;
    const int n = in_sizes[0];

    int nc = n / 4096;
    bool done = false;
    if ((n % 4096) == 0 && nc >= 1 && ws_size >= (size_t)7 * nc * sizeof(double)) {
        int nb = 0;
        hipError_t e1 = hipOccupancyMaxActiveBlocksPerMultiprocessor(
            &nb, rs_coop<16, 4, 12>, THREADS, 0);
        int dev = 0, ncu = 0;
        hipGetDevice(&dev);
        hipError_t e2 = hipDeviceGetAttribute(&ncu, hipDeviceAttributeMultiprocessorCount, dev);
        if (e1 == hipSuccess && e2 == hipSuccess && nb > 0 && ncu > 0) {
            int grid = nb * ncu;
            if (grid > nc) grid = nc;
            if (grid >= 1) {
                void* args[] = {(void*)&in, (void*)&out, (void*)&ws, (void*)&nc};
                hipError_t e3 = hipLaunchCooperativeKernel(
                    (const void*)(rs_coop<16, 4, 12>), dim3(grid), dim3(THREADS),
                    args, 0, stream);
                done = (e3 == hipSuccess);
            }
        }
        if (!done && nc <= 4096) {
            rs_phase1<16, 4><<<nc, THREADS, 0, stream>>>(in, ws, nc);
            rs_phase2<4, 12><<<1, 1024, 0, stream>>>(ws, nc);
            rs_phase3<16, 4><<<nc, THREADS, 0, stream>>>(in, out, ws, nc);
            done = true;
        }
    }
    if (!done) {
        const int nc64 = n / 16384;
        rs_phase1<64, 6><<<nc64, THREADS, 0, stream>>>(in, ws, nc64);
        rs_phase2<1, 14><<<1, 1024, 0, stream>>>(ws, nc64);
        rs_phase3<64, 6><<<nc64, THREADS, 0, stream>>>(in, out, ws, nc64);
    }
}

// Round 6
// 55.022 us; speedup vs baseline: 6.6748x; 3.6831x over previous
//
#include <hip/hip_runtime.h>
#include <math.h>

#define THREADS 256
#define GAMMA 0.99

typedef float vf4 __attribute__((ext_vector_type(4)));   // native vector for nontemporal store

// ---------- padded LDS index: stride PT+1 per thread (odd) -> 2-way banks (free) ----------
template<int LPT>
__device__ __forceinline__ int padi(int i) { return i + (i >> LPT); }

// ---------- block-wide exclusive scan of linear transforms x -> g*x + v ----------
template<int NW>
__device__ __forceinline__ void block_compose_excl(int tid, double g, double v,
                                                   double& eg, double& ev,
                                                   double* lg, double* lv) {
    const int lane = tid & 63, wave = tid >> 6;
    double ig = g, iv = v;
#pragma unroll
    for (int k = 1; k < 64; k <<= 1) {
        double og = __shfl_up(ig, k);
        double ov = __shfl_up(iv, k);
        if (lane >= k) { iv = fma(ig, ov, iv); ig *= og; }
    }
    double weg = __shfl_up(ig, 1);
    double wev = __shfl_up(iv, 1);
    if (lane == 0) { weg = 1.0; wev = 0.0; }
    if (lane == 63) { lg[wave] = ig; lv[wave] = iv; }
    __syncthreads();
    double bg = 1.0, bv = 0.0;
    for (int w = 0; w < wave; ++w) { bv = fma(lg[w], bv, lv[w]); bg *= lg[w]; }
    eg = weg * bg;
    ev = fma(weg, bv, wev);
}

// ---------- block-wide exclusive additive scan of a pair ----------
template<int NW>
__device__ __forceinline__ void block_add_excl2(int tid, double a, double b,
                                                double& ea, double& eb,
                                                double* la, double* lb) {
    const int lane = tid & 63, wave = tid >> 6;
    double ia = a, ib = b;
#pragma unroll
    for (int k = 1; k < 64; k <<= 1) {
        double oa = __shfl_up(ia, k);
        double ob = __shfl_up(ib, k);
        if (lane >= k) { ia += oa; ib += ob; }
    }
    double wea = __shfl_up(ia, 1);
    double web = __shfl_up(ib, 1);
    if (lane == 0) { wea = 0.0; web = 0.0; }
    if (lane == 63) { la[wave] = ia; lb[wave] = ib; }
    __syncthreads();
    double ba = 0.0, bb = 0.0;
    for (int w = 0; w < wave; ++w) { ba += la[w]; bb += lb[w]; }
    ea = wea + ba;
    eb = web + bb;
}

// ---------- Phase 1: per-chunk zero-init aggregates, AoS agg[c*4+{A,Ps,Pq,P2}] ----------
template<int PT, int LPT>
__global__ __launch_bounds__(THREADS) void rs_phase1(const float* __restrict__ in,
                                                     double* __restrict__ agg, int nchunk) {
    constexpr int CHUNKE = THREADS * PT;
    __shared__ double lg[4], lv[4], r1[4], r2[4], r3[4];
    const int tid = threadIdx.x, lane = tid & 63, wave = tid >> 6;
    const int chunk = blockIdx.x;
    const float* src = in + (size_t)chunk * CHUNKE + (size_t)tid * PT;

    float rv[PT];
#pragma unroll
    for (int q = 0; q < PT / 4; ++q) {
        const float4 t = ((const float4*)src)[q];
        rv[4 * q] = t.x; rv[4 * q + 1] = t.y; rv[4 * q + 2] = t.z; rv[4 * q + 3] = t.w;
    }
    const float gf = (float)GAMMA;
    float p = 0.f, psum = 0.f, pq = 0.f, p2 = 0.f, gp = 1.f;
#pragma unroll
    for (int j = 0; j < PT; ++j) {
        p = fmaf(gf, p, rv[j]);
        gp *= gf;
        psum += p;
        pq = fmaf(gp, p, pq);
        p2 = fmaf(p, p, p2);
    }
    const double g = GAMMA;
    double gPT = g;
#pragma unroll
    for (int e = 0; e < LPT; ++e) gPT *= gPT;   // g^PT

    double eg, ev;
    block_compose_excl<4>(tid, gPT, (double)p, eg, ev, lg, lv);
    const double rho = ev, gexc = eg;

    const double G1 = g * (1.0 - gPT) / (1.0 - g);
    const double G2 = g * g * (1.0 - gPT * gPT) / (1.0 - g * g);
    double c1 = fma(rho, G1, (double)psum);
    double c2 = gexc * fma(rho, G2, (double)pq);
    double c3 = fma(rho * rho, G2, fma(2.0 * rho, (double)pq, (double)p2));
#pragma unroll
    for (int k = 32; k > 0; k >>= 1) {
        c1 += __shfl_down(c1, k);
        c2 += __shfl_down(c2, k);
        c3 += __shfl_down(c3, k);
    }
    if (lane == 0) { r1[wave] = c1; r2[wave] = c2; r3[wave] = c3; }
    __syncthreads();
    if (tid == 0) {
        double A = 0.0;
#pragma unroll
        for (int w = 0; w < 4; ++w) A = fma(lg[w], A, lv[w]);
        agg[4 * (size_t)chunk + 0] = A;
        agg[4 * (size_t)chunk + 1] = r1[0] + r1[1] + r1[2] + r1[3];
        agg[4 * (size_t)chunk + 2] = r2[0] + r2[1] + r2[2] + r2[3];
        agg[4 * (size_t)chunk + 3] = r3[0] + r3[1] + r3[2] + r3[3];
    }
}

// ---------- Phase 2: scan chunk carries; car[c*3+{Rin,S1C,S2C}] ----------
template<int CPT, int LOG2CHUNK>
__global__ __launch_bounds__(1024) void rs_phase2(const double* __restrict__ agg,
                                                  double* __restrict__ car, int nchunk) {
    __shared__ double lg[16], lv[16], la[16], lb[16];
    const int t = threadIdx.x;
    const double g = GAMMA;
    double gC = g;
#pragma unroll
    for (int e = 0; e < LOG2CHUNK; ++e) gC *= gC;   // g^CHUNKE

    double A[CPT], Ps[CPT], Pq[CPT], P2[CPT];
    const int c0 = t * CPT;
#pragma unroll
    for (int i = 0; i < CPT; ++i) {
        const int c = c0 + i;
        const bool ok = c < nchunk;
        A[i]  = ok ? agg[4 * (size_t)c + 0] : 0.0;
        Ps[i] = ok ? agg[4 * (size_t)c + 1] : 0.0;
        Pq[i] = ok ? agg[4 * (size_t)c + 2] : 0.0;
        P2[i] = ok ? agg[4 * (size_t)c + 3] : 0.0;
    }
    double mg = 1.0, mv = 0.0;
#pragma unroll
    for (int i = 0; i < CPT; ++i) { mv = fma(gC, mv, A[i]); mg *= gC; }

    double eg, ev;
    block_compose_excl<16>(t, mg, mv, eg, ev, lg, lv);

    const double G1C = g * (1.0 - gC) / (1.0 - g);
    const double G2C = g * g * (1.0 - gC * gC) / (1.0 - g * g);
    double Rin[CPT + 1];
    Rin[0] = ev;
    double s1[CPT], s2[CPT];
#pragma unroll
    for (int i = 0; i < CPT; ++i) {
        s1[i] = fma(Rin[i], G1C, Ps[i]);
        s2[i] = fma(Rin[i] * Rin[i], G2C, fma(2.0 * Rin[i], Pq[i], P2[i]));
        Rin[i + 1] = fma(gC, Rin[i], A[i]);
    }
    double ts1 = 0.0, ts2 = 0.0;
#pragma unroll
    for (int i = 0; i < CPT; ++i) { ts1 += s1[i]; ts2 += s2[i]; }
    double ea, eb;
    block_add_excl2<16>(t, ts1, ts2, ea, eb, la, lb);
#pragma unroll
    for (int i = 0; i < CPT; ++i) {
        const int c = c0 + i;
        if (c < nchunk) {
            car[3 * (size_t)c + 0] = Rin[i];
            car[3 * (size_t)c + 1] = ea;
            car[3 * (size_t)c + 2] = eb;
        }
        ea += s1[i];
        eb += s2[i];
    }
}

// ---------- Phase 3: rebase with true carries, emit scaled rewards ----------
template<int PT, int LPT>
__global__ __launch_bounds__(THREADS) void rs_phase3(const float* __restrict__ in,
                                                     float* __restrict__ out,
                                                     const double* __restrict__ car, int nchunk) {
    constexpr int CHUNKE = THREADS * PT;
    __shared__ float sbuf[CHUNKE + THREADS];
    __shared__ double lg[4], lv[4], la[4], lb[4];
    const int tid = threadIdx.x;
    const int chunk = blockIdx.x;
    const float* src = in + (size_t)chunk * CHUNKE + (size_t)tid * PT;

    float rv[PT];
#pragma unroll
    for (int q = 0; q < PT / 4; ++q) {
        const float4 t = ((const float4*)src)[q];
        rv[4 * q] = t.x; rv[4 * q + 1] = t.y; rv[4 * q + 2] = t.z; rv[4 * q + 3] = t.w;
    }
    const float gf = (float)GAMMA;
    float p = 0.f, psum = 0.f, pq = 0.f, p2 = 0.f, gp = 1.f;
#pragma unroll
    for (int j = 0; j < PT; ++j) {
        p = fmaf(gf, p, rv[j]);
        gp *= gf;
        psum += p;
        pq = fmaf(gp, p, pq);
        p2 = fmaf(p, p, p2);
    }
    const double g = GAMMA;
    double gPT = g;
#pragma unroll
    for (int e = 0; e < LPT; ++e) gPT *= gPT;

    double eg, ev;
    block_compose_excl<4>(tid, gPT, (double)p, eg, ev, lg, lv);

    const double RinC = car[3 * (size_t)chunk + 0];
    const double S1C  = car[3 * (size_t)chunk + 1];
    const double S2C  = car[3 * (size_t)chunk + 2];
    const double rin  = fma(eg, RinC, ev);      // true incoming R for this thread's segment

    const double G1 = g * (1.0 - gPT) / (1.0 - g);
    const double G2 = g * g * (1.0 - gPT * gPT) / (1.0 - g * g);
    const double s1 = fma(rin, G1, (double)psum);
    const double s2 = fma(rin * rin, G2, fma(2.0 * rin, (double)pq, (double)p2));
    double ea, eb;
    block_add_excl2<4>(tid, s1, s2, ea, eb, la, lb);
    const double S1b = S1C + ea;
    const double S2b = S2C + eb;

    const int a0 = padi<LPT>(tid * PT);          // = tid*(PT+1)

    if (chunk == 0) {
        // precise f64 epilogue for the small-cnt region (cancellation-sensitive)
        double R = rin, S1 = S1b, S2 = S2b;
        const size_t gbase = (size_t)tid * PT;
        for (int j = 0; j < PT; ++j) {
            const float rf = rv[j];
            R = fma(g, R, (double)rf);
            S1 += R;
            S2 = fma(R, R, S2);
            float ov;
            if (gbase + j == 0) {
                ov = rf;                         // cnt < 2 -> std = 1
            } else {
                const double cnt = (double)(gbase + j + 1);
                const double inv = 1.0 / cnt;
                const double mean = S1 * inv;
                double var = fma(S2, inv, -(mean * mean));
                var = var > 0.0 ? var : 0.0;
                double sd = sqrt(var);
                sd = sd > 1e-8 ? sd : 1e-8;
                ov = (float)((double)rf / sd);
            }
            sbuf[a0 + j] = ov;
        }
    } else {
        // cnt >= CHUNKE+1: var*cnt^2 = S2*cnt - S1^2 has no cancellation ->
        // out = rf * cnt * rsqrt(S2*cnt - S1^2). One v_rsq replaces 2 divs + sqrt.
        float R = (float)rin;
        float ls1 = 0.f, ls2 = 0.f;
        const float S1bf = (float)S1b, S2bf = (float)S2b;
        const float base_cnt = (float)((size_t)chunk * CHUNKE + (size_t)tid * PT);
#pragma unroll
        for (int j = 0; j < PT; ++j) {
            const float rf = rv[j];
            R = fmaf(gf, R, rf);
            ls1 += R;
            ls2 = fmaf(R, R, ls2);
            const float cnt = base_cnt + (float)(j + 1);
            const float S1f = S1bf + ls1;
            const float S2f = S2bf + ls2;
            float t = fmaf(S2f, cnt, -(S1f * S1f));
            t = fmaxf(t, 1e-12f);
            sbuf[a0 + j] = rf * cnt * __builtin_amdgcn_rsqf(t);
        }
    }
    __syncthreads();

    float* dst = out + (size_t)chunk * CHUNKE;
    for (int i = tid * 4; i < CHUNKE; i += THREADS * 4) {
        const int pp = padi<LPT>(i);
        vf4 v;
        v.x = sbuf[pp]; v.y = sbuf[pp + 1]; v.z = sbuf[pp + 2]; v.w = sbuf[pp + 3];
        __builtin_nontemporal_store(v, (vf4*)(dst + i));   // don't evict L3-resident input
    }
}

extern "C" void kernel_launch(void* const* d_in, const int* in_sizes, int n_in,
                              void* d_out, int out_size, void* d_ws, size_t ws_size,
                              hipStream_t stream) {
    (void)n_in; (void)out_size;
    const float* in = (const float*)d_in[0];
    float* out = (float*)d_out;
    double* ws = (double*)d_ws;
    const int n = in_sizes[0];

    const int nc = n / 4096;
    if ((n % 4096) == 0 && nc >= 1 && nc <= 4096 &&
        ws_size >= (size_t)7 * nc * sizeof(double)) {
        double* agg = ws;                       // 4*nc doubles
        double* car = ws + 4 * (size_t)nc;      // 3*nc doubles
        rs_phase1<16, 4><<<nc, THREADS, 0, stream>>>(in, agg, nc);
        rs_phase2<4, 12><<<1, 1024, 0, stream>>>(agg, car, nc);
        rs_phase3<16, 4><<<nc, THREADS, 0, stream>>>(in, out, car, nc);
    } else {
        const int nc64 = n / 16384;
        double* agg = ws;
        double* car = ws + 4 * (size_t)nc64;
        rs_phase1<64, 6><<<nc64, THREADS, 0, stream>>>(in, agg, nc64);
        rs_phase2<4, 14><<<1, 1024, 0, stream>>>(agg, car, nc64);
        rs_phase3<64, 6><<<nc64, THREADS, 0, stream>>>(in, out, car, nc64);
    }
}